// Round 1
// 1966.898 us; speedup vs baseline: 1.1863x; 1.1863x over previous
//
#include <hip/hip_runtime.h>
#include <hip/hip_bf16.h>

typedef unsigned short u16;
typedef __attribute__((ext_vector_type(8))) __bf16 bf16x8;
typedef __attribute__((ext_vector_type(4))) float f32x4;

// async global->LDS, 16B per lane; LDS dest is wave-uniform base + lane*16
#define GLDS16(gsrc, ldst)                                                         \
  __builtin_amdgcn_global_load_lds(                                               \
      (__attribute__((address_space(1))) const void*)(gsrc),                      \
      (__attribute__((address_space(3))) void*)(ldst), 16, 0, 0)

#define BAR() asm volatile("s_barrier" ::: "memory")
#define LG0()                                            \
  {                                                      \
    asm volatile("s_waitcnt lgkmcnt(0)" ::: "memory");   \
    __builtin_amdgcn_sched_barrier(0);                   \
  }
#define VMW2()                                           \
  {                                                      \
    asm volatile("s_waitcnt vmcnt(2)" ::: "memory");     \
    __builtin_amdgcn_sched_barrier(0);                   \
  }
#define VMW0()                                           \
  {                                                      \
    asm volatile("s_waitcnt vmcnt(0)" ::: "memory");     \
    __builtin_amdgcn_sched_barrier(0);                   \
  }

__device__ __forceinline__ float bf2f(u16 u) {
  union { unsigned int i; float f; } v; v.i = ((unsigned int)u) << 16; return v.f;
}
__device__ __forceinline__ u16 f2bf(float f) {
  union { float f; unsigned int i; } v; v.f = f;
  return (u16)((v.i + 0x7fffu + ((v.i >> 16) & 1u)) >> 16);  // RNE
}

// ---------------- f32 -> bf16 convert (x) ----------------
__global__ void cvt_x_kernel(const float4* __restrict__ in, ushort4* __restrict__ out) {
  size_t i = (size_t)blockIdx.x * 256 + threadIdx.x;
  float4 v = in[i];
  ushort4 o;
  o.x = f2bf(v.x); o.y = f2bf(v.y); o.z = f2bf(v.z); o.w = f2bf(v.w);
  out[i] = o;
}

// ---------------- transpose + convert: in f32 [R][C] -> out bf16 [C][R] ----------------
__global__ void tconv_kernel(const float* __restrict__ in, u16* __restrict__ out,
                             int R, int C) {
  __shared__ float tile[64][65];
  const int c0 = blockIdx.x * 64, r0 = blockIdx.y * 64;
  const int tx = threadIdx.x & 63, ty = threadIdx.x >> 6;  // ty 0..3
#pragma unroll
  for (int p = 0; p < 16; ++p) {
    int row = p * 4 + ty;
    tile[row][tx] = in[(size_t)(r0 + row) * C + c0 + tx];
  }
  __syncthreads();
#pragma unroll
  for (int p = 0; p < 16; ++p) {
    int row = p * 4 + ty;  // output row = input col
    out[(size_t)(c0 + row) * R + r0 + tx] = f2bf(tile[tx][row]);
  }
}

// ---------------- 256x256 8-phase GEMM: C[M][N] = A[M][K] * BT[N][K]^T ----------------
// 8 waves (2m x 4n), per-wave 128x64 output, BK=64, double-buffered 128KiB LDS.
// LDS layout: [256 rows][64 k] bf16, 16B chunks XOR-swizzled by (row&7) -> conflict-free
// ds_read_b128. Swizzle applied on the GLOBAL source (LDS dest of global_load_lds is
// linear); ds_read applies the same XOR.
// Schedule per iteration (2 K-tiles t,t+1; t -> buf0, t+1 -> buf1):
//   ph1: rd A0h(t),B0(t)   stage A-h1(t+1)   mma Q(0,0)
//   ph2: rd B1(t)          stage B-h0(t+1)   mma Q(0,1)
//   ph3: rd A1h(t)         stage B-h1(t+1)   mma Q(1,1)
//   ph4: rd B0(t)          stage A-h0(t+2)   mma Q(1,0)   vmcnt(2)
//   ph5..ph8: same on buf1 / tile t+1, staging t+2/t+3 halves.
// vmcnt(2) leaves exactly the newest half-tile in flight across each K-tile boundary;
// every staged region's last LDS reader is >=1 barrier before the staging phase.
__device__ __forceinline__ void lda4(bf16x8 a[4][2], const u16* b0, const u16* b1) {
#pragma unroll
  for (int mt = 0; mt < 4; ++mt) {
    a[mt][0] = *(const bf16x8*)(b0 + mt * 1024);
    a[mt][1] = *(const bf16x8*)(b1 + mt * 1024);
  }
}
__device__ __forceinline__ void ldb2(bf16x8 b[2][2], const u16* b0, const u16* b1) {
#pragma unroll
  for (int nt = 0; nt < 2; ++nt) {
    b[nt][0] = *(const bf16x8*)(b0 + nt * 1024);
    b[nt][1] = *(const bf16x8*)(b1 + nt * 1024);
  }
}
template <int MH, int NH>
__device__ __forceinline__ void mma8(f32x4 acc[8][4], const bf16x8 a[4][2], const bf16x8 b[2][2]) {
  __builtin_amdgcn_s_setprio(1);
#pragma unroll
  for (int mt = 0; mt < 4; ++mt)
#pragma unroll
    for (int nt = 0; nt < 2; ++nt) {
      f32x4 c = acc[MH * 4 + mt][NH * 2 + nt];
      c = __builtin_amdgcn_mfma_f32_16x16x32_bf16(a[mt][0], b[nt][0], c, 0, 0, 0);
      c = __builtin_amdgcn_mfma_f32_16x16x32_bf16(a[mt][1], b[nt][1], c, 0, 0, 0);
      acc[MH * 4 + mt][NH * 2 + nt] = c;
    }
  __builtin_amdgcn_s_setprio(0);
}

__global__ __launch_bounds__(512, 2) void gemm_bt256_kernel(
    const u16* __restrict__ A, const u16* __restrict__ BT,
    float* __restrict__ Cf, u16* __restrict__ Cb, int M, int N, int K,
    int nbm, int nbn) {
  __shared__ __align__(16) u16 As_[2][16384];
  __shared__ __align__(16) u16 Bs_[2][16384];
  u16* As0 = &As_[0][0]; u16* As1 = &As_[1][0];
  u16* Bs0 = &Bs_[0][0]; u16* Bs1 = &Bs_[1][0];

  // --- block -> tile mapping: XCD chunking then bn-fast panels (PW=10) ---
  const int nwg = nbm * nbn;                       // must be %8==0
  int wg = (int)blockIdx.x;
  wg = (wg & 7) * (nwg >> 3) + (wg >> 3);          // bijective XCD swizzle
  const int PW = 10;
  const int per_panel = PW * nbm;
  const int panel = wg / per_panel;
  const int rem = wg - panel * per_panel;
  const int pw = min(PW, nbn - panel * PW);
  const int bn = panel * PW + rem % pw;
  const int bm = rem / pw;
  const int m0 = bm * 256, n0 = bn * 256;

  const int tid = threadIdx.x;
  const int wave = tid >> 6, lane = tid & 63;
  const int quad = lane >> 4, l16 = lane & 15;
  const int wm = wave >> 2, wn = wave & 3;

  // staging source (pre-swizzled so that linear LDS dest holds the swizzled image)
  const int rl = lane >> 3;                         // row-within-8 this lane stages
  const int cs = ((lane & 7) ^ rl) * 8;             // source k-chunk (elements)
  const u16* pA = A + (size_t)(m0 + wave * 8 + rl) * K + cs;
  const u16* pB = BT + (size_t)(n0 + wave * 8 + rl) * K + cs;
  const size_t r64 = (size_t)64 * K, r128 = (size_t)128 * K;

#define STG(p, hofs, kt, lds)                                         \
  {                                                                   \
    GLDS16((p) + (hofs) + (size_t)(kt) * 64, (lds) + wave * 512);     \
    GLDS16((p) + (hofs) + r64 + (size_t)(kt) * 64, (lds) + 4096 + wave * 512); \
  }

  // ds_read addressing: row = (l16-based), chunk = ((ksl<<2)|quad) ^ (l16&7)
  const int eo = l16 & 7;
  const int aoff0 = l16 * 64 + ((quad ^ eo) * 8);
  const int aoff1 = l16 * 64 + (((4 | quad) ^ eo) * 8);
  const u16* Ab0 = As0 + wm * 8192;
  const u16* Ab1 = As1 + wm * 8192;
  const u16* Bb0 = Bs0 + wn * 4096;
  const u16* Bb1 = Bs1 + wn * 4096;

  f32x4 acc[8][4] = {};
  bf16x8 a[4][2], b[2][2];

  const int NIT = K >> 7;  // 2 K-tiles (BK=64) per iteration

  // prologue: tile0 fully + A-h0 of tile1; leave the newest half-tile in flight
  STG(pA, 0, 0, As0);
  STG(pA, r128, 0, As0 + 8192);
  STG(pB, 0, 0, Bs0);
  STG(pB, r128, 0, Bs0 + 8192);
  STG(pA, 0, 1, As1);
  VMW2();
  BAR();

#pragma unroll 1
  for (int it = 0; it < NIT; ++it) {
    const int t = 2 * it;
    const bool sg = (it < NIT - 1);  // prefetch of t+2/t+3 valid

    // ph1: Q(0,0) of t
    lda4(a, Ab0 + aoff0, Ab0 + aoff1);
    ldb2(b, Bb0 + aoff0, Bb0 + aoff1);
    STG(pA, r128, t + 1, As1 + 8192);
    BAR(); LG0();
    mma8<0, 0>(acc, a, b);
    BAR();
    // ph2: Q(0,1)
    ldb2(b, Bb0 + 2048 + aoff0, Bb0 + 2048 + aoff1);
    STG(pB, 0, t + 1, Bs1);
    BAR(); LG0();
    mma8<0, 1>(acc, a, b);
    BAR();
    // ph3: Q(1,1)
    lda4(a, Ab0 + 4096 + aoff0, Ab0 + 4096 + aoff1);
    STG(pB, r128, t + 1, Bs1 + 8192);
    BAR(); LG0();
    mma8<1, 1>(acc, a, b);
    BAR();
    // ph4: Q(1,0)  + K-tile boundary wait
    ldb2(b, Bb0 + aoff0, Bb0 + aoff1);
    if (sg) STG(pA, 0, t + 2, As0);
    BAR(); LG0();
    mma8<1, 0>(acc, a, b);
    if (sg) { VMW2(); } else { VMW0(); }
    BAR();

    // ph5: Q(0,0) of t+1 (buf1)
    lda4(a, Ab1 + aoff0, Ab1 + aoff1);
    ldb2(b, Bb1 + aoff0, Bb1 + aoff1);
    if (sg) STG(pA, r128, t + 2, As0 + 8192);
    BAR(); LG0();
    mma8<0, 0>(acc, a, b);
    BAR();
    // ph6: Q(0,1)
    ldb2(b, Bb1 + 2048 + aoff0, Bb1 + 2048 + aoff1);
    if (sg) STG(pB, 0, t + 2, Bs0);
    BAR(); LG0();
    mma8<0, 1>(acc, a, b);
    BAR();
    // ph7: Q(1,1)
    lda4(a, Ab1 + 4096 + aoff0, Ab1 + 4096 + aoff1);
    if (sg) STG(pB, r128, t + 2, Bs0 + 8192);
    BAR(); LG0();
    mma8<1, 1>(acc, a, b);
    BAR();
    // ph8: Q(1,0) + boundary wait
    ldb2(b, Bb1 + aoff0, Bb1 + aoff1);
    if (sg) STG(pA, 0, t + 3, As1);
    BAR(); LG0();
    mma8<1, 0>(acc, a, b);
    if (sg) { VMW2(); } else { VMW0(); }
    BAR();
  }
#undef STG

  // epilogue: C/D layout col = lane&15, row = quad*4 + r
  const int crow0 = m0 + wm * 128 + quad * 4;
  const int ccol0 = n0 + wn * 64 + l16;
#pragma unroll
  for (int mt = 0; mt < 8; ++mt)
#pragma unroll
    for (int nt = 0; nt < 4; ++nt)
#pragma unroll
      for (int r = 0; r < 4; ++r) {
        int row = crow0 + mt * 16 + r;
        int col = ccol0 + nt * 16;
        float v = acc[mt][nt][r];
        if (Cb) Cb[(size_t)row * N + col] = f2bf(v);
        else    Cf[(size_t)row * N + col] = v;
      }
}

// ---------------- RoPE in-place on q (heads 0..39) and k (heads 40..49) ----------------
__global__ void rope_kernel(u16* __restrict__ qkv, const int* __restrict__ positions) {
  int idx = blockIdx.x * 256 + threadIdx.x;  // 8192*64
  int j = idx & 63, t = idx >> 6;
  // inv_freq = 10000^(-j/64) = 2^(-j * log2(10000)/64)
  float inv = exp2f(-(float)j * 0.20762050593046014f);
  float ang = (float)positions[t] * inv;
  float sn, cs;
  sincosf(ang, &sn, &cs);
  u16* row = qkv + (size_t)t * 7680;
#pragma unroll 2
  for (int h = 0; h < 50; ++h) {
    u16* p1 = row + h * 128 + j;
    float x1 = bf2f(p1[0]), x2 = bf2f(p1[64]);
    p1[0] = f2bf(x1 * cs - x2 * sn);
    p1[64] = f2bf(x2 * cs + x1 * sn);
  }
}

// ---------------- V transpose: qkv v-part [t][kvh][d] -> VT[b][kvh][d][s] ----------------
__global__ void vtrans_kernel(const u16* __restrict__ qkv, u16* __restrict__ vt) {
  __shared__ u16 tile[64][132];
  const int s0 = blockIdx.x * 64, kvh = blockIdx.y, b = blockIdx.z;
  const int tid = threadIdx.x;
#pragma unroll
  for (int p = 0; p < 8; ++p) {
    int sl = p * 8 + (tid >> 5);
    int d = (tid & 31) * 4;
    const u16* src = qkv + (size_t)(b * 1024 + s0 + sl) * 7680 + (50 + kvh) * 128 + d;
    ushort4 v = *(const ushort4*)src;
    tile[sl][d] = v.x; tile[sl][d + 1] = v.y; tile[sl][d + 2] = v.z; tile[sl][d + 3] = v.w;
  }
  __syncthreads();
#pragma unroll
  for (int p = 0; p < 8; ++p) {
    int d = p * 16 + (tid >> 4);
    int sl = (tid & 15) * 4;
    ushort4 v;
    v.x = tile[sl][d]; v.y = tile[sl + 1][d]; v.z = tile[sl + 2][d]; v.w = tile[sl + 3][d];
    u16* dst = vt + ((size_t)((b * 10 + kvh) * 128) + d) * 1024 + s0 + sl;
    *(ushort4*)dst = v;
  }
}

// ---------------- flash attention, causal, GQA 4:1 ----------------
// block = (q_tile 128, head, batch); 4 waves, each owns 32 q rows.
__global__ __launch_bounds__(256, 2) void attn_kernel(
    const u16* __restrict__ qkv, const u16* __restrict__ vt, u16* __restrict__ ao) {
  // K tile 64s x 128d as 4 sub-tiles [64][32] (64B rows -> conflict-free ds_read_b128)
  __shared__ __align__(16) u16 Ks[4][2048];
  // V^T tile 128d x 64s as 2 sub-tiles [128][32]
  __shared__ __align__(16) u16 VTs[2][4096];
  // P per wave: 32q x 64s as 2 sub-tiles [32][32]
  __shared__ __align__(16) u16 Ps[4][2][1024];

  const int tid = threadIdx.x, wave = tid >> 6, lane = tid & 63;
  const int quad = lane >> 4, l16 = lane & 15;
  const int q0 = blockIdx.x * 128, h = blockIdx.y, b = blockIdx.z;
  const int kvh = h >> 2;
  const float SCALE = 0.08838834764831845f;  // 1/sqrt(128)

  // Q fragments in registers: A-operand layout A[m=lane&15][k=quad*8+j]
  bf16x8 qf[2][4];
#pragma unroll
  for (int mt = 0; mt < 2; ++mt) {
    int t = b * 1024 + q0 + wave * 32 + mt * 16 + l16;
    const u16* qrow = qkv + (size_t)t * 7680 + h * 128;
#pragma unroll
    for (int ks = 0; ks < 4; ++ks)
      qf[mt][ks] = *(const bf16x8*)(qrow + ks * 32 + quad * 8);
  }

  f32x4 oa[2][8] = {};
  float mstate[2][4], lstate[2][4];
#pragma unroll
  for (int mt = 0; mt < 2; ++mt)
#pragma unroll
    for (int r = 0; r < 4; ++r) { mstate[mt][r] = -1e30f; lstate[mt][r] = 0.f; }

  const u16* Kbase = qkv + (size_t)(b * 1024) * 7680 + (40 + kvh) * 128;
  const u16* VTbase = vt + (size_t)((b * 10 + kvh) * 128) * 1024;

  const int nsteps = q0 / 64 + 2;
  for (int step = 0; step < nsteps; ++step) {
    const int s0 = step * 64;
    __syncthreads();  // previous iteration's LDS reads done
#pragma unroll
    for (int j = 0; j < 4; ++j) {
      int c = 4 * wave + j;
      int ksub = c >> 2, rg = c & 3;
      GLDS16(Kbase + (size_t)(s0 + rg * 16 + (lane >> 2)) * 7680 + ksub * 32 + (lane & 3) * 8,
             &Ks[ksub][rg * 512]);
      int vsub = c >> 3, dg = c & 7;
      GLDS16(VTbase + (size_t)(dg * 16 + (lane >> 2)) * 1024 + s0 + vsub * 32 + (lane & 3) * 8,
             &VTs[vsub][dg * 512]);
    }
    __syncthreads();  // staging visible (vmcnt drained by barrier)

    // S = Q K^T  (rows m=q, cols n=s)
    f32x4 sa[2][4] = {};
#pragma unroll
    for (int ks = 0; ks < 4; ++ks) {
      bf16x8 kb[4];
#pragma unroll
      for (int nt = 0; nt < 4; ++nt)
        kb[nt] = *(const bf16x8*)&Ks[ks][(nt * 16 + l16) * 32 + quad * 8];
#pragma unroll
      for (int mt = 0; mt < 2; ++mt)
#pragma unroll
        for (int nt = 0; nt < 4; ++nt)
          sa[mt][nt] = __builtin_amdgcn_mfma_f32_16x16x32_bf16(qf[mt][ks], kb[nt], sa[mt][nt], 0, 0, 0);
    }

    // online softmax per q row (rows live in C-layout: row = quad*4+r)
#pragma unroll
    for (int mt = 0; mt < 2; ++mt) {
#pragma unroll
      for (int r = 0; r < 4; ++r) {
        int qg = q0 + wave * 32 + mt * 16 + quad * 4 + r;
        float pv[4];
        float rowmax = -1e30f;
#pragma unroll
        for (int nt = 0; nt < 4; ++nt) {
          int sg = s0 + nt * 16 + l16;
          float v = sa[mt][nt][r] * SCALE;
          if (sg > qg) v = -1e30f;
          pv[nt] = v;
          rowmax = fmaxf(rowmax, v);
        }
#pragma unroll
        for (int off = 1; off < 16; off <<= 1)
          rowmax = fmaxf(rowmax, __shfl_xor(rowmax, off));
        float mnew = fmaxf(mstate[mt][r], rowmax);
        float alpha = __expf(mstate[mt][r] - mnew);
        mstate[mt][r] = mnew;
        float rs = 0.f;
#pragma unroll
        for (int nt = 0; nt < 4; ++nt) {
          float p = __expf(pv[nt] - mnew);
          rs += p;
          Ps[wave][nt >> 1][(mt * 16 + quad * 4 + r) * 32 + (nt & 1) * 16 + l16] = f2bf(p);
        }
#pragma unroll
        for (int off = 1; off < 16; off <<= 1)
          rs += __shfl_xor(rs, off);
        lstate[mt][r] = lstate[mt][r] * alpha + rs;
#pragma unroll
        for (int ntd = 0; ntd < 8; ++ntd) oa[mt][ntd][r] *= alpha;
      }
    }
    __syncthreads();  // P writes visible

    // O += P V  (A = P[q][s], B = V[s][d] read from VT sub-tiles)
#pragma unroll
    for (int ks2 = 0; ks2 < 2; ++ks2) {
      bf16x8 pf[2];
#pragma unroll
      for (int mt = 0; mt < 2; ++mt)
        pf[mt] = *(const bf16x8*)&Ps[wave][ks2][(mt * 16 + l16) * 32 + quad * 8];
#pragma unroll
      for (int ntd = 0; ntd < 8; ++ntd) {
        bf16x8 vf = *(const bf16x8*)&VTs[ks2][(ntd * 16 + l16) * 32 + quad * 8];
#pragma unroll
        for (int mt = 0; mt < 2; ++mt)
          oa[mt][ntd] = __builtin_amdgcn_mfma_f32_16x16x32_bf16(pf[mt], vf, oa[mt][ntd], 0, 0, 0);
      }
    }
  }

  // epilogue: O / l -> ao[t][h][d] bf16
#pragma unroll
  for (int mt = 0; mt < 2; ++mt)
#pragma unroll
    for (int ntd = 0; ntd < 8; ++ntd)
#pragma unroll
      for (int r = 0; r < 4; ++r) {
        int t = b * 1024 + q0 + wave * 32 + mt * 16 + quad * 4 + r;
        int d = ntd * 16 + l16;
        float v = oa[mt][ntd][r] / lstate[mt][r];
        ao[((size_t)t * 40 + h) * 128 + d] = f2bf(v);
      }
}

// ---------------- launch ----------------
extern "C" void kernel_launch(void* const* d_in, const int* in_sizes, int n_in,
                              void* d_out, int out_size, void* d_ws, size_t ws_size,
                              hipStream_t stream) {
  const float* x = (const float*)d_in[0];
  const float* wqkv = (const float*)d_in[1];
  const float* wo = (const float*)d_in[2];
  const int* pos = (const int*)d_in[3];
  float* out = (float*)d_out;

  char* ws = (char*)d_ws;
  // layout (bytes): xb 83,886,080 (reused as attn-out) | wT 78,643,200 (reused as woT)
  //                 | qkv 125,829,120 | vt 20,971,520  => total 309,329,920
  u16* xb = (u16*)(ws);
  u16* wT = (u16*)(ws + 83886080);
  u16* qkvb = (u16*)(ws + 83886080 + 78643200);
  u16* vt = (u16*)(ws + 83886080 + 78643200 + 125829120);

  cvt_x_kernel<<<40960, 256, 0, stream>>>((const float4*)x, (ushort4*)xb);
  tconv_kernel<<<dim3(120, 80), 256, 0, stream>>>(wqkv, wT, 5120, 7680);
  gemm_bt256_kernel<<<32 * 30, 512, 0, stream>>>(xb, wT, nullptr, qkvb, 8192, 7680, 5120, 32, 30);
  rope_kernel<<<2048, 256, 0, stream>>>(qkvb, pos);
  vtrans_kernel<<<dim3(16, 10, 8), 256, 0, stream>>>(qkvb, vt);
  tconv_kernel<<<dim3(80, 80), 256, 0, stream>>>(wo, wT, 5120, 5120);  // wT now = w_o^T
  attn_kernel<<<dim3(8, 40, 8), 256, 0, stream>>>(qkvb, vt, xb);       // xb now = attn out
  gemm_bt256_kernel<<<32 * 20, 512, 0, stream>>>(xb, wT, out, nullptr, 8192, 5120, 5120, 32, 20);
}

// Round 2
// 1932.764 us; speedup vs baseline: 1.2073x; 1.0177x over previous
//
#include <hip/hip_runtime.h>
#include <hip/hip_bf16.h>

typedef unsigned short u16;
typedef __attribute__((ext_vector_type(8))) __bf16 bf16x8;
typedef __attribute__((ext_vector_type(4))) float f32x4;

// async global->LDS, 16B per lane; LDS dest is wave-uniform base + lane*16
#define GLDS16(gsrc, ldst)                                                         \
  __builtin_amdgcn_global_load_lds(                                               \
      (__attribute__((address_space(1))) const void*)(gsrc),                      \
      (__attribute__((address_space(3))) void*)(ldst), 16, 0, 0)

#define BAR() asm volatile("s_barrier" ::: "memory")
#define LGK(N)                                                      \
  {                                                                 \
    asm volatile("s_waitcnt lgkmcnt(" #N ")" ::: "memory");         \
    __builtin_amdgcn_sched_barrier(0);                              \
  }
#define VMW(N)                                                      \
  {                                                                 \
    asm volatile("s_waitcnt vmcnt(" #N ")" ::: "memory");           \
    __builtin_amdgcn_sched_barrier(0);                              \
  }

__device__ __forceinline__ float bf2f(u16 u) {
  union { unsigned int i; float f; } v; v.i = ((unsigned int)u) << 16; return v.f;
}
__device__ __forceinline__ u16 f2bf(float f) {
  union { float f; unsigned int i; } v; v.f = f;
  return (u16)((v.i + 0x7fffu + ((v.i >> 16) & 1u)) >> 16);  // RNE
}

// ---------------- f32 -> bf16 convert (x) ----------------
__global__ void cvt_x_kernel(const float4* __restrict__ in, ushort4* __restrict__ out) {
  size_t i = (size_t)blockIdx.x * 256 + threadIdx.x;
  float4 v = in[i];
  ushort4 o;
  o.x = f2bf(v.x); o.y = f2bf(v.y); o.z = f2bf(v.z); o.w = f2bf(v.w);
  out[i] = o;
}

// ---------------- transpose + convert: in f32 [R][C] -> out bf16 [C][R] ----------------
__global__ void tconv_kernel(const float* __restrict__ in, u16* __restrict__ out,
                             int R, int C) {
  __shared__ float tile[64][65];
  const int c0 = blockIdx.x * 64, r0 = blockIdx.y * 64;
  const int tx = threadIdx.x & 63, ty = threadIdx.x >> 6;  // ty 0..3
#pragma unroll
  for (int p = 0; p < 16; ++p) {
    int row = p * 4 + ty;
    tile[row][tx] = in[(size_t)(r0 + row) * C + c0 + tx];
  }
  __syncthreads();
#pragma unroll
  for (int p = 0; p < 16; ++p) {
    int row = p * 4 + ty;  // output row = input col
    out[(size_t)(c0 + row) * R + r0 + tx] = f2bf(tile[tx][row]);
  }
}

// ---------------- 256x256 GEMM, register-pipelined 4-phase schedule -------------------
// C[M][N] = A[M][K] * BT[N][K]^T. 8 waves (2m x 4n), per-wave 128x64, BK=64,
// double-buffered 128KiB LDS, st-swizzled (bank-conflict-free, verified R1).
// Per K-tile t (buf R=t&1), quadrants Q00,Q01,Q11,Q10; ds_reads issued ONE PHASE EARLY
// with counted lgkmcnt so they overlap the previous MFMA cluster:
//   p1: [STG Ah1(t+1)->bufN] rd B1(t)          lgkm(4)  mma Q00(a0,B0)
//   p2: rd A1(t)                               lgkm(8)  mma Q01(a0,B1)   BAR
//   p3: [STG Bh0(t+2)->bufR]                   lgkm(0)  mma Q11(a1,B1)   VMW(2) BAR
//   p4: rd A0(t+1),B0(t+1) (from bufN, post-VMW-BAR)  [STG Bh1,Ah0(t+2)] mma Q10(a1,B0)
// B0 is kept live in registers across the tile (no re-read); B0/B1 register slots swap
// roles every tile (loop unrolled x2). Region safety: every staged region's last reader
// completes at a counted-lgkm >=1 barrier before the stage; newest stage of tile t+1
// (Ah1 @p1(t)) is 2 phases before its VMW(2) requirement @p3(t).
__device__ __forceinline__ void lda4(bf16x8 a[4][2], const u16* b0, const u16* b1) {
#pragma unroll
  for (int mt = 0; mt < 4; ++mt) {
    a[mt][0] = *(const bf16x8*)(b0 + mt * 1024);
    a[mt][1] = *(const bf16x8*)(b1 + mt * 1024);
  }
}
__device__ __forceinline__ void ldb2(bf16x8 b[2][2], const u16* b0, const u16* b1) {
#pragma unroll
  for (int nt = 0; nt < 2; ++nt) {
    b[nt][0] = *(const bf16x8*)(b0 + nt * 1024);
    b[nt][1] = *(const bf16x8*)(b1 + nt * 1024);
  }
}
template <int MH, int NH>
__device__ __forceinline__ void mma8(f32x4 acc[8][4], const bf16x8 a[4][2], const bf16x8 b[2][2]) {
  __builtin_amdgcn_s_setprio(1);
#pragma unroll
  for (int mt = 0; mt < 4; ++mt)
#pragma unroll
    for (int nt = 0; nt < 2; ++nt) {
      f32x4 c = acc[MH * 4 + mt][NH * 2 + nt];
      c = __builtin_amdgcn_mfma_f32_16x16x32_bf16(a[mt][0], b[nt][0], c, 0, 0, 0);
      c = __builtin_amdgcn_mfma_f32_16x16x32_bf16(a[mt][1], b[nt][1], c, 0, 0, 0);
      acc[MH * 4 + mt][NH * 2 + nt] = c;
    }
  __builtin_amdgcn_s_setprio(0);
}

__global__ __launch_bounds__(512, 2) void gemm_bt256_kernel(
    const u16* __restrict__ A, const u16* __restrict__ BT,
    float* __restrict__ Cf, u16* __restrict__ Cb, int M, int N, int K,
    int nbm, int nbn) {
  __shared__ __align__(16) u16 As_[2][16384];
  __shared__ __align__(16) u16 Bs_[2][16384];
  u16* As0 = &As_[0][0]; u16* As1 = &As_[1][0];
  u16* Bs0 = &Bs_[0][0]; u16* Bs1 = &Bs_[1][0];

  // --- block -> tile mapping: XCD chunking then bn-fast panels (PW=10) ---
  const int nwg = nbm * nbn;                       // must be %8==0
  int wg = (int)blockIdx.x;
  wg = (wg & 7) * (nwg >> 3) + (wg >> 3);          // bijective XCD swizzle
  const int PW = 10;
  const int per_panel = PW * nbm;
  const int panel = wg / per_panel;
  const int rem = wg - panel * per_panel;
  const int pw = min(PW, nbn - panel * PW);
  const int bn = panel * PW + rem % pw;
  const int bm = rem / pw;
  const int m0 = bm * 256, n0 = bn * 256;

  const int tid = threadIdx.x;
  const int wave = tid >> 6, lane = tid & 63;
  const int quad = lane >> 4, l16 = lane & 15;
  const int wm = wave >> 2, wn = wave & 3;

  // staging source (pre-swizzled so that linear LDS dest holds the swizzled image)
  const int rl = lane >> 3;                         // row-within-8 this lane stages
  const int cs = ((lane & 7) ^ rl) * 8;             // source k-chunk (elements)
  const u16* pA = A + (size_t)(m0 + wave * 8 + rl) * K + cs;
  const u16* pB = BT + (size_t)(n0 + wave * 8 + rl) * K + cs;
  const size_t r64 = (size_t)64 * K, r128 = (size_t)128 * K;

#define STG(p, hofs, kt, lds)                                         \
  {                                                                   \
    GLDS16((p) + (hofs) + (size_t)(kt) * 64, (lds) + wave * 512);     \
    GLDS16((p) + (hofs) + r64 + (size_t)(kt) * 64, (lds) + 4096 + wave * 512); \
  }

  // ds_read addressing: row = (l16-based), chunk = ((ksl<<2)|quad) ^ (l16&7)
  const int eo = l16 & 7;
  const int aoff0 = l16 * 64 + ((quad ^ eo) * 8);
  const int aoff1 = l16 * 64 + (((4 | quad) ^ eo) * 8);
  const u16* Ab0 = As0 + wm * 8192;
  const u16* Ab1 = As1 + wm * 8192;
  const u16* Bb0 = Bs0 + wn * 4096;
  const u16* Bb1 = Bs1 + wn * 4096;

  f32x4 acc[8][4] = {};
  bf16x8 a0[4][2], a1[4][2], bx[2][2], by[2][2];

  const int NT = K >> 6;  // K-tiles of BK=64 (must be even)

  // prologue: tile0 fully into buf0; Bh0,Bh1,Ah0 of tile1 into buf1 (steady-state image)
  STG(pA, 0, 0, As0);
  STG(pA, r128, 0, As0 + 8192);
  STG(pB, 0, 0, Bs0);
  STG(pB, r128, 0, Bs0 + 8192);
  STG(pB, 0, 1, Bs1);
  STG(pB, r128, 1, Bs1 + 8192);
  STG(pA, 0, 1, As1);
  VMW(6);
  BAR();
  lda4(a0, Ab0 + aoff0, Ab0 + aoff1);  // A0(0)
  ldb2(bx, Bb0 + aoff0, Bb0 + aoff1);  // B0(0)
  __builtin_amdgcn_sched_barrier(0);

#define TILE(t, AbR, BbR, AbN, BbN, AsN, AsR, BsR, B0r, B1r)                   \
  {                                                                            \
    const bool sg1 = (t) + 1 < NT, sg2 = (t) + 2 < NT;                         \
    /* p1 */                                                                   \
    if (sg1) STG(pA, r128, (t) + 1, (AsN) + 8192);                             \
    ldb2(B1r, (BbR) + 2048 + aoff0, (BbR) + 2048 + aoff1);                     \
    LGK(4);                                                                    \
    mma8<0, 0>(acc, a0, B0r);                                                  \
    /* p2 */                                                                   \
    lda4(a1, (AbR) + 4096 + aoff0, (AbR) + 4096 + aoff1);                      \
    LGK(8);                                                                    \
    mma8<0, 1>(acc, a0, B1r);                                                  \
    BAR();                                                                     \
    /* p3 */                                                                   \
    if (sg2) STG(pB, 0, (t) + 2, (BsR));                                       \
    LGK(0);                                                                    \
    mma8<1, 1>(acc, a1, B1r);                                                  \
    if (sg2) { VMW(2); } else { VMW(0); }                                      \
    BAR();                                                                     \
    /* p4 */                                                                   \
    if (sg1) {                                                                 \
      lda4(a0, (AbN) + aoff0, (AbN) + aoff1);                                  \
      ldb2(B1r, (BbN) + aoff0, (BbN) + aoff1);                                 \
    }                                                                          \
    if (sg2) {                                                                 \
      STG(pB, r128, (t) + 2, (BsR) + 8192);                                    \
      STG(pA, 0, (t) + 2, (AsR));                                              \
    }                                                                          \
    __builtin_amdgcn_sched_barrier(0);                                         \
    mma8<1, 0>(acc, a1, B0r);                                                  \
  }

#pragma unroll 1
  for (int it = 0; it < (NT >> 1); ++it) {
    const int t = 2 * it;
    TILE(t, Ab0, Bb0, Ab1, Bb1, As1, As0, Bs0, bx, by);
    TILE(t + 1, Ab1, Bb1, Ab0, Bb0, As0, As1, Bs1, by, bx);
  }
#undef TILE
#undef STG

  // epilogue: C/D layout col = lane&15, row = quad*4 + r
  const int crow0 = m0 + wm * 128 + quad * 4;
  const int ccol0 = n0 + wn * 64 + l16;
#pragma unroll
  for (int mt = 0; mt < 8; ++mt)
#pragma unroll
    for (int nt = 0; nt < 4; ++nt)
#pragma unroll
      for (int r = 0; r < 4; ++r) {
        int row = crow0 + mt * 16 + r;
        int col = ccol0 + nt * 16;
        float v = acc[mt][nt][r];
        if (Cb) Cb[(size_t)row * N + col] = f2bf(v);
        else    Cf[(size_t)row * N + col] = v;
      }
}

// ---------------- RoPE in-place on q (heads 0..39) and k (heads 40..49) ----------------
__global__ void rope_kernel(u16* __restrict__ qkv, const int* __restrict__ positions) {
  int idx = blockIdx.x * 256 + threadIdx.x;  // 8192*64
  int j = idx & 63, t = idx >> 6;
  // inv_freq = 10000^(-j/64) = 2^(-j * log2(10000)/64)
  float inv = exp2f(-(float)j * 0.20762050593046014f);
  float ang = (float)positions[t] * inv;
  float sn, cs;
  sincosf(ang, &sn, &cs);
  u16* row = qkv + (size_t)t * 7680;
#pragma unroll 2
  for (int h = 0; h < 50; ++h) {
    u16* p1 = row + h * 128 + j;
    float x1 = bf2f(p1[0]), x2 = bf2f(p1[64]);
    p1[0] = f2bf(x1 * cs - x2 * sn);
    p1[64] = f2bf(x2 * cs + x1 * sn);
  }
}

// ---------------- V transpose: qkv v-part [t][kvh][d] -> VT[b][kvh][d][s] ----------------
__global__ void vtrans_kernel(const u16* __restrict__ qkv, u16* __restrict__ vt) {
  __shared__ u16 tile[64][132];
  const int s0 = blockIdx.x * 64, kvh = blockIdx.y, b = blockIdx.z;
  const int tid = threadIdx.x;
#pragma unroll
  for (int p = 0; p < 8; ++p) {
    int sl = p * 8 + (tid >> 5);
    int d = (tid & 31) * 4;
    const u16* src = qkv + (size_t)(b * 1024 + s0 + sl) * 7680 + (50 + kvh) * 128 + d;
    ushort4 v = *(const ushort4*)src;
    tile[sl][d] = v.x; tile[sl][d + 1] = v.y; tile[sl][d + 2] = v.z; tile[sl][d + 3] = v.w;
  }
  __syncthreads();
#pragma unroll
  for (int p = 0; p < 8; ++p) {
    int d = p * 16 + (tid >> 4);
    int sl = (tid & 15) * 4;
    ushort4 v;
    v.x = tile[sl][d]; v.y = tile[sl + 1][d]; v.z = tile[sl + 2][d]; v.w = tile[sl + 3][d];
    u16* dst = vt + ((size_t)((b * 10 + kvh) * 128) + d) * 1024 + s0 + sl;
    *(ushort4*)dst = v;
  }
}

// ---------------- flash attention, causal, GQA 4:1 ----------------
// block = (q_tile 128, head, batch); 4 waves, each owns 32 q rows.
__global__ __launch_bounds__(256, 2) void attn_kernel(
    const u16* __restrict__ qkv, const u16* __restrict__ vt, u16* __restrict__ ao) {
  // K tile 64s x 128d as 4 sub-tiles [64][32] (64B rows -> conflict-free ds_read_b128)
  __shared__ __align__(16) u16 Ks[4][2048];
  // V^T tile 128d x 64s as 2 sub-tiles [128][32]
  __shared__ __align__(16) u16 VTs[2][4096];
  // P per wave: 32q x 64s as 2 sub-tiles [32][32]
  __shared__ __align__(16) u16 Ps[4][2][1024];

  const int tid = threadIdx.x, wave = tid >> 6, lane = tid & 63;
  const int quad = lane >> 4, l16 = lane & 15;
  const int q0 = blockIdx.x * 128, h = blockIdx.y, b = blockIdx.z;
  const int kvh = h >> 2;
  const float SCALE = 0.08838834764831845f;  // 1/sqrt(128)

  // Q fragments in registers: A-operand layout A[m=lane&15][k=quad*8+j]
  bf16x8 qf[2][4];
#pragma unroll
  for (int mt = 0; mt < 2; ++mt) {
    int t = b * 1024 + q0 + wave * 32 + mt * 16 + l16;
    const u16* qrow = qkv + (size_t)t * 7680 + h * 128;
#pragma unroll
    for (int ks = 0; ks < 4; ++ks)
      qf[mt][ks] = *(const bf16x8*)(qrow + ks * 32 + quad * 8);
  }

  f32x4 oa[2][8] = {};
  float mstate[2][4], lstate[2][4];
#pragma unroll
  for (int mt = 0; mt < 2; ++mt)
#pragma unroll
    for (int r = 0; r < 4; ++r) { mstate[mt][r] = -1e30f; lstate[mt][r] = 0.f; }

  const u16* Kbase = qkv + (size_t)(b * 1024) * 7680 + (40 + kvh) * 128;
  const u16* VTbase = vt + (size_t)((b * 10 + kvh) * 128) * 1024;

  const int nsteps = q0 / 64 + 2;
  for (int step = 0; step < nsteps; ++step) {
    const int s0 = step * 64;
    __syncthreads();  // previous iteration's LDS reads done
#pragma unroll
    for (int j = 0; j < 4; ++j) {
      int c = 4 * wave + j;
      int ksub = c >> 2, rg = c & 3;
      GLDS16(Kbase + (size_t)(s0 + rg * 16 + (lane >> 2)) * 7680 + ksub * 32 + (lane & 3) * 8,
             &Ks[ksub][rg * 512]);
      int vsub = c >> 3, dg = c & 7;
      GLDS16(VTbase + (size_t)(dg * 16 + (lane >> 2)) * 1024 + s0 + vsub * 32 + (lane & 3) * 8,
             &VTs[vsub][dg * 512]);
    }
    __syncthreads();  // staging visible (vmcnt drained by barrier)

    // S = Q K^T  (rows m=q, cols n=s)
    f32x4 sa[2][4] = {};
#pragma unroll
    for (int ks = 0; ks < 4; ++ks) {
      bf16x8 kb[4];
#pragma unroll
      for (int nt = 0; nt < 4; ++nt)
        kb[nt] = *(const bf16x8*)&Ks[ks][(nt * 16 + l16) * 32 + quad * 8];
#pragma unroll
      for (int mt = 0; mt < 2; ++mt)
#pragma unroll
        for (int nt = 0; nt < 4; ++nt)
          sa[mt][nt] = __builtin_amdgcn_mfma_f32_16x16x32_bf16(qf[mt][ks], kb[nt], sa[mt][nt], 0, 0, 0);
    }

    // online softmax per q row (rows live in C-layout: row = quad*4+r)
#pragma unroll
    for (int mt = 0; mt < 2; ++mt) {
#pragma unroll
      for (int r = 0; r < 4; ++r) {
        int qg = q0 + wave * 32 + mt * 16 + quad * 4 + r;
        float pv[4];
        float rowmax = -1e30f;
#pragma unroll
        for (int nt = 0; nt < 4; ++nt) {
          int sg = s0 + nt * 16 + l16;
          float v = sa[mt][nt][r] * SCALE;
          if (sg > qg) v = -1e30f;
          pv[nt] = v;
          rowmax = fmaxf(rowmax, v);
        }
#pragma unroll
        for (int off = 1; off < 16; off <<= 1)
          rowmax = fmaxf(rowmax, __shfl_xor(rowmax, off));
        float mnew = fmaxf(mstate[mt][r], rowmax);
        float alpha = __expf(mstate[mt][r] - mnew);
        mstate[mt][r] = mnew;
        float rs = 0.f;
#pragma unroll
        for (int nt = 0; nt < 4; ++nt) {
          float p = __expf(pv[nt] - mnew);
          rs += p;
          Ps[wave][nt >> 1][(mt * 16 + quad * 4 + r) * 32 + (nt & 1) * 16 + l16] = f2bf(p);
        }
#pragma unroll
        for (int off = 1; off < 16; off <<= 1)
          rs += __shfl_xor(rs, off);
        lstate[mt][r] = lstate[mt][r] * alpha + rs;
#pragma unroll
        for (int ntd = 0; ntd < 8; ++ntd) oa[mt][ntd][r] *= alpha;
      }
    }
    __syncthreads();  // P writes visible

    // O += P V  (A = P[q][s], B = V[s][d] read from VT sub-tiles)
#pragma unroll
    for (int ks2 = 0; ks2 < 2; ++ks2) {
      bf16x8 pf[2];
#pragma unroll
      for (int mt = 0; mt < 2; ++mt)
        pf[mt] = *(const bf16x8*)&Ps[wave][ks2][(mt * 16 + l16) * 32 + quad * 8];
#pragma unroll
      for (int ntd = 0; ntd < 8; ++ntd) {
        bf16x8 vf = *(const bf16x8*)&VTs[ks2][(ntd * 16 + l16) * 32 + quad * 8];
#pragma unroll
        for (int mt = 0; mt < 2; ++mt)
          oa[mt][ntd] = __builtin_amdgcn_mfma_f32_16x16x32_bf16(pf[mt], vf, oa[mt][ntd], 0, 0, 0);
      }
    }
  }

  // epilogue: O / l -> ao[t][h][d] bf16
#pragma unroll
  for (int mt = 0; mt < 2; ++mt)
#pragma unroll
    for (int ntd = 0; ntd < 8; ++ntd)
#pragma unroll
      for (int r = 0; r < 4; ++r) {
        int t = b * 1024 + q0 + wave * 32 + mt * 16 + quad * 4 + r;
        int d = ntd * 16 + l16;
        float v = oa[mt][ntd][r] / lstate[mt][r];
        ao[((size_t)t * 40 + h) * 128 + d] = f2bf(v);
      }
}

// ---------------- launch ----------------
extern "C" void kernel_launch(void* const* d_in, const int* in_sizes, int n_in,
                              void* d_out, int out_size, void* d_ws, size_t ws_size,
                              hipStream_t stream) {
  const float* x = (const float*)d_in[0];
  const float* wqkv = (const float*)d_in[1];
  const float* wo = (const float*)d_in[2];
  const int* pos = (const int*)d_in[3];
  float* out = (float*)d_out;

  char* ws = (char*)d_ws;
  // layout (bytes): xb 83,886,080 (reused as attn-out) | wT 78,643,200 (reused as woT)
  //                 | qkv 125,829,120 | vt 20,971,520  => total 309,329,920
  u16* xb = (u16*)(ws);
  u16* wT = (u16*)(ws + 83886080);
  u16* qkvb = (u16*)(ws + 83886080 + 78643200);
  u16* vt = (u16*)(ws + 83886080 + 78643200 + 125829120);

  cvt_x_kernel<<<40960, 256, 0, stream>>>((const float4*)x, (ushort4*)xb);
  tconv_kernel<<<dim3(120, 80), 256, 0, stream>>>(wqkv, wT, 5120, 7680);
  gemm_bt256_kernel<<<32 * 30, 512, 0, stream>>>(xb, wT, nullptr, qkvb, 8192, 7680, 5120, 32, 30);
  rope_kernel<<<2048, 256, 0, stream>>>(qkvb, pos);
  vtrans_kernel<<<dim3(16, 10, 8), 256, 0, stream>>>(qkvb, vt);
  tconv_kernel<<<dim3(80, 80), 256, 0, stream>>>(wo, wT, 5120, 5120);  // wT now = w_o^T
  attn_kernel<<<dim3(8, 40, 8), 256, 0, stream>>>(qkvb, vt, xb);       // xb now = attn out
  gemm_bt256_kernel<<<32 * 20, 512, 0, stream>>>(xb, wT, out, nullptr, 8192, 5120, 5120, 32, 20);
}